// Round 2
// baseline (27536.359 us; speedup 1.0000x reference)
//
#include <hip/hip_runtime.h>
#include <cstddef>

#define BB 64
#define LL 512
#define II 256
#define HH 512

typedef _Float16 f16;
typedef _Float16 f16x8 __attribute__((ext_vector_type(8)));
typedef float f32x4 __attribute__((ext_vector_type(4)));

// ws layout in f16 units:
//   W0F  @ 0        : [j=16][kb=16][tn=2][L=64][e=8]  = 262144  (512KB)
//   W1F  @ 262144   : same                             = 262144
//   WGF  @ 524288   : [j=16][kb=24][tt=6][L=64][e=8]  = 1179648 (2.25MB)
//   YBUF @ 1703936  : [c=4][p=2][m=16][col=512]        = 65536
//   FLAGS@ byte 3538944 : 4 x unsigned
#define W0F_H 0
#define W1F_H 262144
#define WGF_H 524288
#define YBUF_H 1703936
#define FLAGS_B 3538944
#define N0 262144
#define N1 262144
#define N2 1179648
#define N3 32768
#define PREP_TOTAL (N0 + N1 + N2 + N3 + 4)

__global__ void prep_kernel(const float* __restrict__ dw0, const float* __restrict__ dw1,
                            const float* __restrict__ w_ih, const float* __restrict__ w_hh,
                            const float* __restrict__ h0, f16* __restrict__ wsh) {
    int idx = blockIdx.x * 256 + threadIdx.x;
    if (idx < N0 + N1) {
        const float* src = (idx < N0) ? dw0 : dw1;
        int r = (idx < N0) ? idx : idx - N0;
        int e = r & 7, L = (r >> 3) & 63, tn = (r >> 9) & 1, kb = (r >> 10) & 15, j = r >> 14;
        int n = j * 32 + tn * 16 + (L & 15);
        int k = kb * 32 + (L >> 4) * 8 + e;
        wsh[idx] = (f16)src[n * 512 + k];
        return;
    }
    idx -= (N0 + N1);
    if (idx < N2) {
        int e = idx & 7, L = (idx >> 3) & 63;
        int rest = idx >> 9;
        int tt = rest % 6, r2 = rest / 6;
        int kb = r2 % 24, j = r2 / 24;
        int g = tt >> 1, tn = tt & 1;
        int n = g * 512 + j * 32 + tn * 16 + (L & 15);
        int kc = kb * 32 + (L >> 4) * 8 + e;
        float v = (kc < 256) ? w_ih[n * 256 + kc] : w_hh[n * 512 + (kc - 256)];
        wsh[WGF_H + idx] = (f16)v;
        return;
    }
    idx -= N2;
    if (idx < N3) {
        // ybuf[c][p=0][m][col] = h0[col]
        int col = idx & 511, m = (idx >> 9) & 15, c = idx >> 13;
        wsh[YBUF_H + (size_t)c * 16384 + m * 512 + col] = (f16)h0[col];
        return;
    }
    idx -= N3;
    if (idx < 4) ((unsigned*)((char*)wsh + FLAGS_B))[idx] = 0u;
}

__device__ __forceinline__ void cluster_sync(unsigned* flag, unsigned q) {
    __syncthreads();  // drains each wave's vmcnt before barrier -> stores are in L2
    if (threadIdx.x == 0) {
        __threadfence();  // agent release: write back L2 so other XCDs see our slice
        __hip_atomic_fetch_add(flag, 1u, __ATOMIC_RELEASE, __HIP_MEMORY_SCOPE_AGENT);
        unsigned target = 16u * (q + 1u);
        while (__hip_atomic_load(flag, __ATOMIC_ACQUIRE, __HIP_MEMORY_SCOPE_AGENT) < target)
            __builtin_amdgcn_s_sleep(1);
        __threadfence();  // agent acquire: invalidate stale L1/L2 lines
    }
    __syncthreads();
}

// stage full 16x512 f16 activation vector from global ping-pong buffer into LDS (pad 520)
__device__ __forceinline__ void stageA(const f16* __restrict__ rbuf, f16* __restrict__ A, int tid) {
    int m = tid >> 5, o = tid & 31;
    f16x8 v0 = *(const f16x8*)&rbuf[m * 512 + o * 16];
    f16x8 v1 = *(const f16x8*)&rbuf[m * 512 + o * 16 + 8];
    *(f16x8*)&A[m * 520 + o * 16] = v0;
    *(f16x8*)&A[m * 520 + o * 16 + 8] = v1;
}

// ODE matvec: this wave's partial C for tile tn=w&1 over kb in [kh*4, kh*4+4)
__device__ __forceinline__ f32x4 ode_mm(const f16* __restrict__ Ws, const f16* __restrict__ A,
                                        int w, int L) {
    const int tn = w & 1, kh = w >> 1;
    const int L15 = L & 15, Lq = L >> 4;
    f32x4 acc = {0.f, 0.f, 0.f, 0.f};
#pragma unroll
    for (int i = 0; i < 4; ++i) {
        int kb = kh * 4 + i;
        f16x8 a = *(const f16x8*)&A[L15 * 520 + kb * 32 + Lq * 8];
        f16x8 b = *(const f16x8*)&Ws[(kb * 2 + tn) * 512 + L * 8];
        acc = __builtin_amdgcn_mfma_f32_16x16x32_f16(a, b, acc, 0, 0, 0);
    }
    return acc;
}

__launch_bounds__(512, 1)
__global__ void odegru_kernel(const float* __restrict__ x, const float* __restrict__ tds,
                              const float* __restrict__ b_ih, const float* __restrict__ b_hh,
                              const float* __restrict__ db0, const float* __restrict__ db1,
                              const float* __restrict__ h0, const int* __restrict__ seq_lens,
                              f16* __restrict__ wsh, float* __restrict__ out) {
    __shared__ f16 W0s[16384];     // 32KB: this CU's 32-col slice of W0, frag-linear
    __shared__ f16 W1s[16384];     // 32KB
    __shared__ f16 Abuf[16 * 520]; // staged activation rows (padded)
    __shared__ f16 Xbuf[16 * 264]; // staged x_t rows (padded)
    __shared__ float Red[3 * 2 * 64 * 4];  // K-split partials [kh-1][tn][L][r]
    __shared__ float Gate[8 * 64 * 4];     // GRU gate exchange [slot][L][r]
    __shared__ float tdS[16];
    __shared__ int slS[16];

    const int tid = threadIdx.x;
    const int w = tid >> 6;
    const int L = tid & 63;
    const int L15 = L & 15;
    const int Lq = L >> 4;
    const int bid = blockIdx.x;
    const int c = bid & 3;       // cluster (batch-row group)
    const int j = bid >> 2;      // N-slice owner within cluster (0..15)
    const int b0 = c * 16;

    unsigned* flag = (unsigned*)((char*)wsh + FLAGS_B) + c;
    f16* yb0 = wsh + YBUF_H + (size_t)c * 16384;  // two ping-pong buffers of 8192 f16

    // load W0/W1 slices into LDS (already per-j frag-linear in ws)
    {
        const f16* w0g = wsh + W0F_H + (size_t)j * 16384;
        const f16* w1g = wsh + W1F_H + (size_t)j * 16384;
        for (int i = tid; i < 2048; i += 512) {
            *(f16x8*)&W0s[i * 8] = *(const f16x8*)&w0g[i * 8];
            *(f16x8*)&W1s[i * 8] = *(const f16x8*)&w1g[i * 8];
        }
    }
    // GRU fused-weight slice -> registers (24 x 16B per lane, waves 0..5)
    f16x8 wgr[24];
    if (w < 6) {
        const f16* wgg = wsh + WGF_H;
#pragma unroll
        for (int kb = 0; kb < 24; ++kb)
            wgr[kb] = *(const f16x8*)&wgg[((((size_t)j * 24 + kb) * 6 + w) * 64 + L) * 8];
    }
    // per-lane state (waves 0,1 own hidden cols col = j*32 + w*16 + L15)
    float h[4], k1[4], k2[4], k3[4], hode[4];
    float d0b = 0.f, d1b = 0.f, bir = 0.f, bhr = 0.f, biz = 0.f, bhz = 0.f, bin_ = 0.f, bhn = 0.f;
    int col = j * 32 + (w & 1) * 16 + L15;
    if (w < 2) {
        float hv = h0[col];
#pragma unroll
        for (int r = 0; r < 4; ++r) h[r] = hv;
        d0b = db0[col]; d1b = db1[col];
        bir = b_ih[col];        bhr = b_hh[col];
        biz = b_ih[512 + col];  bhz = b_hh[512 + col];
        bin_ = b_ih[1024 + col]; bhn = b_hh[1024 + col];
    }
    if (tid < 16) slS[tid] = seq_lens[b0 + tid];
    __syncthreads();

    for (int t = 0; t < LL; ++t) {
        const int qb = t * 9;
        // ---- stage x_t (masked) and td ----
        {
            int m = tid >> 5, o = tid & 31;
            bool valid = t < slS[m];
            const float* xp = x + ((size_t)(b0 + m) * LL + t) * II + o * 8;
            f16x8 xv;
            if (valid) {
                f32x4 xa = *(const f32x4*)xp;
                f32x4 xb = *(const f32x4*)(xp + 4);
#pragma unroll
                for (int e = 0; e < 4; ++e) { xv[e] = (f16)xa[e]; xv[4 + e] = (f16)xb[e]; }
            } else {
#pragma unroll
                for (int e = 0; e < 8; ++e) xv[e] = (f16)0.f;
            }
            *(f16x8*)&Xbuf[m * 264 + o * 8] = xv;
            if (tid < 16) tdS[tid] = (t < slS[tid]) ? tds[(size_t)(b0 + tid) * LL + t] : 0.f;
        }
        __syncthreads();

        // ---- 4 RK4 stages, 2 passes each ----
#pragma unroll 1
        for (int s = 0; s < 4; ++s) {
            // W0 pass: u = tanh(y W0^T + db0)
            {
                const int q = qb + 2 * s;
                const f16* rbuf = yb0 + (q & 1) * 8192;
                f16* wbuf = yb0 + ((q & 1) ^ 1) * 8192;
                stageA(rbuf, Abuf, tid);
                __syncthreads();
                f32x4 acc = ode_mm(W0s, Abuf, w, L);
                if (w >= 2) {
#pragma unroll
                    for (int r = 0; r < 4; ++r)
                        Red[(((w >> 1) - 1) * 2 + (w & 1)) * 256 + L * 4 + r] = acc[r];
                }
                __syncthreads();
                if (w < 2) {
#pragma unroll
                    for (int p = 0; p < 3; ++p)
#pragma unroll
                        for (int r = 0; r < 4; ++r) acc[r] += Red[(p * 2 + w) * 256 + L * 4 + r];
#pragma unroll
                    for (int r = 0; r < 4; ++r) {
                        float u = tanhf(acc[r] + d0b);
                        wbuf[(Lq * 4 + r) * 512 + col] = (f16)u;
                    }
                }
                cluster_sync(flag, (unsigned)q);
            }
            // W1 pass: k = tanh(u W1^T + db1) * td; update state; emit next y
            {
                const int q = qb + 2 * s + 1;
                const f16* rbuf = yb0 + (q & 1) * 8192;
                f16* wbuf = yb0 + ((q & 1) ^ 1) * 8192;
                stageA(rbuf, Abuf, tid);
                __syncthreads();
                f32x4 acc = ode_mm(W1s, Abuf, w, L);
                if (w >= 2) {
#pragma unroll
                    for (int r = 0; r < 4; ++r)
                        Red[(((w >> 1) - 1) * 2 + (w & 1)) * 256 + L * 4 + r] = acc[r];
                }
                __syncthreads();
                if (w < 2) {
#pragma unroll
                    for (int p = 0; p < 3; ++p)
#pragma unroll
                        for (int r = 0; r < 4; ++r) acc[r] += Red[(p * 2 + w) * 256 + L * 4 + r];
#pragma unroll
                    for (int r = 0; r < 4; ++r) {
                        float kv = tanhf(acc[r] + d1b) * tdS[Lq * 4 + r];
                        float yv;
                        if (s == 0)      { k1[r] = kv; yv = h[r] + kv * (1.f / 3.f); }
                        else if (s == 1) { k2[r] = kv; yv = h[r] + kv - k1[r] * (1.f / 3.f); }
                        else if (s == 2) { k3[r] = kv; yv = h[r] + k1[r] - k2[r] + kv; }
                        else { hode[r] = h[r] + (k1[r] + 3.f * (k2[r] + k3[r]) + kv) * 0.125f;
                               yv = hode[r]; }
                        wbuf[(Lq * 4 + r) * 512 + col] = (f16)yv;
                    }
                }
                cluster_sync(flag, (unsigned)q);
            }
        }

        // ---- GRU pass: gates = [x | h_ode] @ [Wih ; Whh]^T (K=768) ----
        {
            const int q = qb + 8;
            const f16* rbuf = yb0 + (q & 1) * 8192;
            f16* wbuf = yb0 + ((q & 1) ^ 1) * 8192;
            stageA(rbuf, Abuf, tid);  // h_ode rows
            __syncthreads();
            f32x4 aA = {0.f, 0.f, 0.f, 0.f};  // x-part
            f32x4 aB = {0.f, 0.f, 0.f, 0.f};  // h-part
            if (w < 6) {
#pragma unroll
                for (int kb = 0; kb < 8; ++kb) {
                    f16x8 a = *(const f16x8*)&Xbuf[L15 * 264 + kb * 32 + Lq * 8];
                    aA = __builtin_amdgcn_mfma_f32_16x16x32_f16(a, wgr[kb], aA, 0, 0, 0);
                }
#pragma unroll
                for (int kb = 8; kb < 24; ++kb) {
                    f16x8 a = *(const f16x8*)&Abuf[L15 * 520 + (kb - 8) * 32 + Lq * 8];
                    aB = __builtin_amdgcn_mfma_f32_16x16x32_f16(a, wgr[kb], aB, 0, 0, 0);
                }
            }
            if (w < 4) {
#pragma unroll
                for (int r = 0; r < 4; ++r) Gate[w * 256 + L * 4 + r] = aA[r] + aB[r];
            } else if (w < 6) {
#pragma unroll
                for (int r = 0; r < 4; ++r) {
                    Gate[w * 256 + L * 4 + r] = aA[r];        // i_n raw (slots 4,5)
                    Gate[(w + 2) * 256 + L * 4 + r] = aB[r];  // h_n raw (slots 6,7)
                }
            }
            __syncthreads();
            if (w < 2) {
#pragma unroll
                for (int r = 0; r < 4; ++r) {
                    float g0  = Gate[(0 + w) * 256 + L * 4 + r];
                    float g1  = Gate[(2 + w) * 256 + L * 4 + r];
                    float gix = Gate[(4 + w) * 256 + L * 4 + r];
                    float ghn = Gate[(6 + w) * 256 + L * 4 + r];
                    float rg = 1.f / (1.f + __expf(-(g0 + bir + bhr)));
                    float z  = 1.f / (1.f + __expf(-(g1 + biz + bhz)));
                    float nn = tanhf(gix + bin_ + rg * (ghn + bhn));
                    float hn = (1.f - z) * nn + z * hode[r];
                    h[r] = hn;
                    int m = Lq * 4 + r;
                    out[((size_t)(b0 + m) * LL + t) * HH + col] = hn;
                    wbuf[m * 512 + col] = (f16)hn;
                }
            }
            cluster_sync(flag, (unsigned)q);
        }
    }
}

__global__ void finalize_kernel(const int* __restrict__ seq_lens, float* __restrict__ out) {
    int b = blockIdx.x;
    int n = threadIdx.x;
    int sl = seq_lens[b];
    out[(size_t)BB * LL * HH + (size_t)b * HH + n] =
        out[((size_t)b * LL + (sl - 1)) * HH + n];
}

extern "C" void kernel_launch(void* const* d_in, const int* in_sizes, int n_in,
                              void* d_out, int out_size, void* d_ws, size_t ws_size,
                              hipStream_t stream) {
    const float* x    = (const float*)d_in[0];
    const float* tds  = (const float*)d_in[1];
    const float* w_ih = (const float*)d_in[2];
    const float* w_hh = (const float*)d_in[3];
    const float* b_ih = (const float*)d_in[4];
    const float* b_hh = (const float*)d_in[5];
    const float* dw0  = (const float*)d_in[6];
    const float* db0  = (const float*)d_in[7];
    const float* dw1  = (const float*)d_in[8];
    const float* db1  = (const float*)d_in[9];
    const float* h0   = (const float*)d_in[10];
    const int* seq_lens = (const int*)d_in[11];
    float* out = (float*)d_out;
    f16* wsh = (f16*)d_ws;

    prep_kernel<<<(PREP_TOTAL + 255) / 256, 256, 0, stream>>>(dw0, dw1, w_ih, w_hh, h0, wsh);
    odegru_kernel<<<64, 512, 0, stream>>>(x, tds, b_ih, b_hh, db0, db1, h0, seq_lens, wsh, out);
    finalize_kernel<<<BB, HH, 0, stream>>>(seq_lens, out);
}

// Round 4
// 9184.420 us; speedup vs baseline: 2.9982x; 2.9982x over previous
//
#include <hip/hip_runtime.h>
#include <cstddef>

#define BB 64
#define LL 512
#define II 256
#define HH 512

typedef _Float16 f16;
typedef _Float16 f16x8 __attribute__((ext_vector_type(8)));
typedef float f32x4 __attribute__((ext_vector_type(4)));

// ws layout in f16 units:
//   W0F  @ 0        : [j=16][kb=16][tn=2][L=64][e=8]  = 262144  (512KB)
//   W1F  @ 262144   : same                             = 262144
//   WGF  @ 524288   : [j=16][kb=24][tt=6][L=64][e=8]  = 1179648 (2.25MB)
//   YBUF @ 1703936  : [c=4][p=2][m=16][col=512]        = 65536
// byte offsets:
//   FLAGS @ 3538944 : 4 clusters x 256B (16 slots x 16B)
#define W0F_H 0
#define W1F_H 262144
#define WGF_H 524288
#define YBUF_H 1703936
#define FLAGS_B 3538944
#define N0 262144
#define N1 262144
#define N2 1179648
#define N3 32768
#define N4 256
#define PREP_TOTAL (N0 + N1 + N2 + N3 + N4)

__global__ void prep_kernel(const float* __restrict__ dw0, const float* __restrict__ dw1,
                            const float* __restrict__ w_ih, const float* __restrict__ w_hh,
                            const float* __restrict__ h0, f16* __restrict__ wsh) {
    int idx = blockIdx.x * 256 + threadIdx.x;
    if (idx >= PREP_TOTAL) return;
    if (idx < N0 + N1) {
        const float* src = (idx < N0) ? dw0 : dw1;
        int r = (idx < N0) ? idx : idx - N0;
        int e = r & 7, L = (r >> 3) & 63, tn = (r >> 9) & 1, kb = (r >> 10) & 15, j = r >> 14;
        int n = j * 32 + tn * 16 + (L & 15);
        int k = kb * 32 + (L >> 4) * 8 + e;
        wsh[idx] = (f16)src[n * 512 + k];
        return;
    }
    idx -= (N0 + N1);
    if (idx < N2) {
        int e = idx & 7, L = (idx >> 3) & 63;
        int rest = idx >> 9;
        int tt = rest % 6, r2 = rest / 6;
        int kb = r2 % 24, j = r2 / 24;
        int g = tt >> 1, tn = tt & 1;
        int n = g * 512 + j * 32 + tn * 16 + (L & 15);
        int kc = kb * 32 + (L >> 4) * 8 + e;
        float v = (kc < 256) ? w_ih[n * 256 + kc] : w_hh[n * 512 + (kc - 256)];
        wsh[WGF_H + idx] = (f16)v;
        return;
    }
    idx -= N2;
    if (idx < N3) {
        int col = idx & 511, m = (idx >> 9) & 15, c = idx >> 13;
        wsh[YBUF_H + (size_t)c * 16384 + m * 512 + col] = (f16)h0[col];
        return;
    }
    idx -= N3;
    ((unsigned*)((char*)wsh + FLAGS_B))[idx] = 0u;  // zero 4x64 flag uints
}

// sc0 sc1 accesses are device-coherent at the Infinity Cache (sc1 stores write
// through the per-XCD L2; sc1 loads bypass stale L1/L2). Relaxed agent-scope
// visibility per the gfx94x memory model needs NO buffer_inv / buffer_wbl2.
__device__ __forceinline__ void st_u32_sc(unsigned* p, unsigned v) {
    asm volatile("global_store_dword %0, %1, off sc0 sc1" :: "v"(p), "v"(v) : "memory");
}
__device__ __forceinline__ unsigned ld_u32_sc(const unsigned* p) {
    unsigned v;
    asm volatile("global_load_dword %0, %1, off sc0 sc1\n\ts_waitcnt vmcnt(0)"
                 : "=v"(v) : "v"(p) : "memory");
    return v;
}
__device__ __forceinline__ void st_f16_sc(f16* p, f16 v) {
    unsigned u = (unsigned)__builtin_bit_cast(unsigned short, v);
    asm volatile("global_store_short %0, %1, off sc0 sc1" :: "v"(p), "v"(u) : "memory");
}

// __syncthreads() drains each wave's vmcnt -> all prior sc1 stores are
// device-visible; then post our slot and poll all 16 slots (16B stride).
__device__ __forceinline__ void cluster_sync(unsigned* slots, int j, unsigned target, int tid) {
    __syncthreads();
    if (tid == 0) st_u32_sc(slots + j * 4, target);
    if (tid < 16) {
        while (ld_u32_sc(slots + tid * 4) < target) __builtin_amdgcn_s_sleep(1);
    }
    __syncthreads();
}

// stage 16x512 f16 activations from the cluster ping-pong buffer (sc0 sc1)
__device__ __forceinline__ void stageA_sc(const f16* __restrict__ rbuf, f16* __restrict__ A,
                                          int tid) {
    int m = tid >> 5, o = tid & 31;
    const f16* p = &rbuf[m * 512 + o * 16];
    f32x4 v0, v1;
    asm volatile("global_load_dwordx4 %0, %2, off sc0 sc1\n\t"
                 "global_load_dwordx4 %1, %2, off offset:16 sc0 sc1\n\t"
                 "s_waitcnt vmcnt(0)"
                 : "=&v"(v0), "=&v"(v1) : "v"(p) : "memory");
    *(f32x4*)&A[m * 520 + o * 16] = v0;
    *(f32x4*)&A[m * 520 + o * 16 + 8] = v1;
}

// ODE matvec: this wave's partial C for tile tn=w&1 over kb in [kh*4, kh*4+4)
__device__ __forceinline__ f32x4 ode_mm(const f16* __restrict__ Ws, const f16* __restrict__ A,
                                        int w, int L) {
    const int tn = w & 1, kh = w >> 1;
    const int L15 = L & 15, Lq = L >> 4;
    f32x4 acc = {0.f, 0.f, 0.f, 0.f};
#pragma unroll
    for (int i = 0; i < 4; ++i) {
        int kb = kh * 4 + i;
        f16x8 a = *(const f16x8*)&A[L15 * 520 + kb * 32 + Lq * 8];
        f16x8 b = *(const f16x8*)&Ws[(kb * 2 + tn) * 512 + L * 8];
        acc = __builtin_amdgcn_mfma_f32_16x16x32_f16(a, b, acc, 0, 0, 0);
    }
    return acc;
}

__launch_bounds__(512, 1)
__global__ void odegru_kernel(const float* __restrict__ x, const float* __restrict__ tds,
                              const float* __restrict__ b_ih, const float* __restrict__ b_hh,
                              const float* __restrict__ db0, const float* __restrict__ db1,
                              const float* __restrict__ h0, const int* __restrict__ seq_lens,
                              f16* __restrict__ wsh, float* __restrict__ out) {
    __shared__ f16 W0s[16384];
    __shared__ f16 W1s[16384];
    __shared__ f16 Abuf[16 * 520];
    __shared__ f16 Xbuf[16 * 264];
    __shared__ float Red[3 * 2 * 64 * 4];
    __shared__ float Gate[8 * 64 * 4];
    __shared__ float tdS[16];
    __shared__ int slS[16];

    const int tid = threadIdx.x;
    const int w = tid >> 6;
    const int L = tid & 63;
    const int L15 = L & 15;
    const int Lq = L >> 4;
    const int bid = blockIdx.x;
    const int c = bid & 3;       // fixed cluster (no placement assumptions)
    const int j = bid >> 2;      // N-slice owner within cluster (0..15)
    const int b0 = c * 16;

    unsigned* slots = (unsigned*)((char*)wsh + FLAGS_B + (size_t)c * 256);
    f16* yb0 = wsh + YBUF_H + (size_t)c * 16384;

    {
        const f16* w0g = wsh + W0F_H + (size_t)j * 16384;
        const f16* w1g = wsh + W1F_H + (size_t)j * 16384;
        for (int i = tid; i < 2048; i += 512) {
            *(f16x8*)&W0s[i * 8] = *(const f16x8*)&w0g[i * 8];
            *(f16x8*)&W1s[i * 8] = *(const f16x8*)&w1g[i * 8];
        }
    }
    f16x8 wgr[24];
    if (w < 6) {
        const f16* wgg = wsh + WGF_H;
#pragma unroll
        for (int kb = 0; kb < 24; ++kb)
            wgr[kb] = *(const f16x8*)&wgg[((((size_t)j * 24 + kb) * 6 + w) * 64 + L) * 8];
    }
    float h[4], k1[4], k2[4], k3[4], hode[4];
    float d0b = 0.f, d1b = 0.f, bir = 0.f, bhr = 0.f, biz = 0.f, bhz = 0.f, bin_ = 0.f, bhn = 0.f;
    int col = j * 32 + (w & 1) * 16 + L15;
    if (w < 2) {
        float hv = h0[col];
#pragma unroll
        for (int r = 0; r < 4; ++r) h[r] = hv;
        d0b = db0[col]; d1b = db1[col];
        bir = b_ih[col];        bhr = b_hh[col];
        biz = b_ih[512 + col];  bhz = b_hh[512 + col];
        bin_ = b_ih[1024 + col]; bhn = b_hh[1024 + col];
    }
    if (tid < 16) slS[tid] = seq_lens[b0 + tid];
    __syncthreads();

    for (int t = 0; t < LL; ++t) {
        const int qb = t * 9;
        {
            int m = tid >> 5, o = tid & 31;
            bool valid = t < slS[m];
            const float* xp = x + ((size_t)(b0 + m) * LL + t) * II + o * 8;
            f16x8 xv;
            if (valid) {
                f32x4 xa = *(const f32x4*)xp;
                f32x4 xb = *(const f32x4*)(xp + 4);
#pragma unroll
                for (int e = 0; e < 4; ++e) { xv[e] = (f16)xa[e]; xv[4 + e] = (f16)xb[e]; }
            } else {
#pragma unroll
                for (int e = 0; e < 8; ++e) xv[e] = (f16)0.f;
            }
            *(f16x8*)&Xbuf[m * 264 + o * 8] = xv;
            if (tid < 16) tdS[tid] = (t < slS[tid]) ? tds[(size_t)(b0 + tid) * LL + t] : 0.f;
        }
        __syncthreads();

#pragma unroll 1
        for (int s = 0; s < 4; ++s) {
            {
                const int q = qb + 2 * s;
                const f16* rbuf = yb0 + (q & 1) * 8192;
                f16* wbuf = yb0 + ((q & 1) ^ 1) * 8192;
                stageA_sc(rbuf, Abuf, tid);
                __syncthreads();
                f32x4 acc = ode_mm(W0s, Abuf, w, L);
                if (w >= 2) {
#pragma unroll
                    for (int r = 0; r < 4; ++r)
                        Red[(((w >> 1) - 1) * 2 + (w & 1)) * 256 + L * 4 + r] = acc[r];
                }
                __syncthreads();
                if (w < 2) {
#pragma unroll
                    for (int p = 0; p < 3; ++p)
#pragma unroll
                        for (int r = 0; r < 4; ++r) acc[r] += Red[(p * 2 + w) * 256 + L * 4 + r];
#pragma unroll
                    for (int r = 0; r < 4; ++r) {
                        float u = tanhf(acc[r] + d0b);
                        st_f16_sc(&wbuf[(Lq * 4 + r) * 512 + col], (f16)u);
                    }
                }
                cluster_sync(slots, j, (unsigned)(q + 1), tid);
            }
            {
                const int q = qb + 2 * s + 1;
                const f16* rbuf = yb0 + (q & 1) * 8192;
                f16* wbuf = yb0 + ((q & 1) ^ 1) * 8192;
                stageA_sc(rbuf, Abuf, tid);
                __syncthreads();
                f32x4 acc = ode_mm(W1s, Abuf, w, L);
                if (w >= 2) {
#pragma unroll
                    for (int r = 0; r < 4; ++r)
                        Red[(((w >> 1) - 1) * 2 + (w & 1)) * 256 + L * 4 + r] = acc[r];
                }
                __syncthreads();
                if (w < 2) {
#pragma unroll
                    for (int p = 0; p < 3; ++p)
#pragma unroll
                        for (int r = 0; r < 4; ++r) acc[r] += Red[(p * 2 + w) * 256 + L * 4 + r];
#pragma unroll
                    for (int r = 0; r < 4; ++r) {
                        float kv = tanhf(acc[r] + d1b) * tdS[Lq * 4 + r];
                        float yv;
                        if (s == 0)      { k1[r] = kv; yv = h[r] + kv * (1.f / 3.f); }
                        else if (s == 1) { k2[r] = kv; yv = h[r] + kv - k1[r] * (1.f / 3.f); }
                        else if (s == 2) { k3[r] = kv; yv = h[r] + k1[r] - k2[r] + kv; }
                        else { hode[r] = h[r] + (k1[r] + 3.f * (k2[r] + k3[r]) + kv) * 0.125f;
                               yv = hode[r]; }
                        st_f16_sc(&wbuf[(Lq * 4 + r) * 512 + col], (f16)yv);
                    }
                }
                cluster_sync(slots, j, (unsigned)(q + 1), tid);
            }
        }

        {
            const int q = qb + 8;
            const f16* rbuf = yb0 + (q & 1) * 8192;
            f16* wbuf = yb0 + ((q & 1) ^ 1) * 8192;
            stageA_sc(rbuf, Abuf, tid);
            __syncthreads();
            f32x4 aA = {0.f, 0.f, 0.f, 0.f};
            f32x4 aB = {0.f, 0.f, 0.f, 0.f};
            if (w < 6) {
#pragma unroll
                for (int kb = 0; kb < 8; ++kb) {
                    f16x8 a = *(const f16x8*)&Xbuf[L15 * 264 + kb * 32 + Lq * 8];
                    aA = __builtin_amdgcn_mfma_f32_16x16x32_f16(a, wgr[kb], aA, 0, 0, 0);
                }
#pragma unroll
                for (int kb = 8; kb < 24; ++kb) {
                    f16x8 a = *(const f16x8*)&Abuf[L15 * 520 + (kb - 8) * 32 + Lq * 8];
                    aB = __builtin_amdgcn_mfma_f32_16x16x32_f16(a, wgr[kb], aB, 0, 0, 0);
                }
            }
            if (w < 4) {
#pragma unroll
                for (int r = 0; r < 4; ++r) Gate[w * 256 + L * 4 + r] = aA[r] + aB[r];
            } else if (w < 6) {
#pragma unroll
                for (int r = 0; r < 4; ++r) {
                    Gate[w * 256 + L * 4 + r] = aA[r];
                    Gate[(w + 2) * 256 + L * 4 + r] = aB[r];
                }
            }
            __syncthreads();
            if (w < 2) {
#pragma unroll
                for (int r = 0; r < 4; ++r) {
                    float g0  = Gate[(0 + w) * 256 + L * 4 + r];
                    float g1  = Gate[(2 + w) * 256 + L * 4 + r];
                    float gix = Gate[(4 + w) * 256 + L * 4 + r];
                    float ghn = Gate[(6 + w) * 256 + L * 4 + r];
                    float rg = 1.f / (1.f + __expf(-(g0 + bir + bhr)));
                    float z  = 1.f / (1.f + __expf(-(g1 + biz + bhz)));
                    float nn = tanhf(gix + bin_ + rg * (ghn + bhn));
                    float hn = (1.f - z) * nn + z * hode[r];
                    h[r] = hn;
                    int m = Lq * 4 + r;
                    out[((size_t)(b0 + m) * LL + t) * HH + col] = hn;
                    st_f16_sc(&wbuf[m * 512 + col], (f16)hn);
                }
            }
            cluster_sync(slots, j, (unsigned)(q + 1), tid);
        }
    }
}

__global__ void finalize_kernel(const int* __restrict__ seq_lens, float* __restrict__ out) {
    int b = blockIdx.x;
    int n = threadIdx.x;
    int sl = seq_lens[b];
    out[(size_t)BB * LL * HH + (size_t)b * HH + n] =
        out[((size_t)b * LL + (sl - 1)) * HH + n];
}

extern "C" void kernel_launch(void* const* d_in, const int* in_sizes, int n_in,
                              void* d_out, int out_size, void* d_ws, size_t ws_size,
                              hipStream_t stream) {
    const float* x    = (const float*)d_in[0];
    const float* tds  = (const float*)d_in[1];
    const float* w_ih = (const float*)d_in[2];
    const float* w_hh = (const float*)d_in[3];
    const float* b_ih = (const float*)d_in[4];
    const float* b_hh = (const float*)d_in[5];
    const float* dw0  = (const float*)d_in[6];
    const float* db0  = (const float*)d_in[7];
    const float* dw1  = (const float*)d_in[8];
    const float* db1  = (const float*)d_in[9];
    const float* h0   = (const float*)d_in[10];
    const int* seq_lens = (const int*)d_in[11];
    float* out = (float*)d_out;
    f16* wsh = (f16*)d_ws;

    prep_kernel<<<(PREP_TOTAL + 255) / 256, 256, 0, stream>>>(dw0, dw1, w_ih, w_hh, h0, wsh);
    odegru_kernel<<<64, 512, 0, stream>>>(x, tds, b_ih, b_hh, db0, db1, h0, seq_lens, wsh, out);
    finalize_kernel<<<BB, HH, 0, stream>>>(seq_lens, out);
}